// Round 3
// baseline (170.189 us; speedup 1.0000x reference)
//
#include <hip/hip_runtime.h>
#include <math.h>

#define KK 64
#define CAP 64
#define NF 4160      // 64 targets x (1 self + up to 64 in-edge slots)
#define BMW 1568     // bitmask words for 50k nodes (50176 bits)

// ---------------- Pass A (read-only): find edges incident to `node`; fused zeroing ----------------
// Early-exit: exactly KK incident edges exist; once tcount reads KK the scan is skipped.
__global__ __launch_bounds__(256) void k_find(const int* __restrict__ ei, int E,
                                              const int* __restrict__ nodep,
                                              int4* __restrict__ zbase, int zcount4,
                                              int* __restrict__ tcount,
                                              int* __restrict__ tpairs) {
    int idx = blockIdx.x * 256 + threadIdx.x;
    if (idx < zcount4) zbase[idx] = make_int4(0, 0, 0, 0);   // cnt/fmapRow/fcnt/tcnt2/aux
    int node = nodep[0];
    int n4 = E >> 2;
    if (idx < n4) {
        int found = __hip_atomic_load(tcount, __ATOMIC_RELAXED, __HIP_MEMORY_SCOPE_AGENT);
        if (found < KK) {    // value only grows 0->KK; stale-low just means we scan (correct)
            int4 ss = ((const int4*)ei)[idx];
            int4 dd = ((const int4*)(ei + E))[idx];
            int s[4] = {ss.x, ss.y, ss.z, ss.w};
            int d[4] = {dd.x, dd.y, dd.z, dd.w};
#pragma unroll
            for (int k = 0; k < 4; k++) {
                if (s[k] == node || d[k] == node) {
                    int q = atomicAdd(tcount, 1);
                    if (q < KK) { int e = idx * 4 + k; tpairs[2 * q] = e; tpairs[2 * q + 1] = (s[k] == node) ? d[k] : s[k]; }
                }
            }
        }
    }
    if (idx == 0) {
        for (int e = n4 * 4; e < E; e++) {
            int s = ei[e], d = ei[E + e];
            if (s == node || d == node) {
                int q = atomicAdd(tcount, 1);
                if (q < KK) { tpairs[2 * q] = e; tpairs[2 * q + 1] = (s == node) ? d : s; }
            }
        }
    }
}

// ---------------- Pass B: target collect + HALF degree atomics + fmapRow claims ----------------
__global__ __launch_bounds__(256) void k_collect_t(const int* __restrict__ ei, int E,
                                                   const int* __restrict__ tpairs,
                                                   int* __restrict__ cnt,
                                                   int* __restrict__ tcnt2,
                                                   int* __restrict__ tslots,
                                                   int* __restrict__ fmapRow,
                                                   int* __restrict__ tsorted_g,
                                                   int* __restrict__ towner_g) {
    __shared__ unsigned int bmask[BMW];
    __shared__ int tnode[KK];
    __shared__ int eidx[KK], tgt[KK], srt[KK];
    int tid = threadIdx.x;
    for (int i = tid; i < BMW; i += 256) bmask[i] = 0u;
    if (tid < KK) { eidx[tid] = tpairs[2 * tid]; tgt[tid] = tpairs[2 * tid + 1]; }
    __syncthreads();
    if (tid < KK) {
        int rank = 0;
        for (int j = 0; j < KK; j++) rank += (eidx[j] < eidx[tid]) ? 1 : 0;
        srt[rank] = tgt[tid];
    }
    __syncthreads();
    if (tid < KK) {
        int mynode = srt[tid];
        int owner = tid;
        for (int j = 0; j < tid; j++) if (srt[j] == mynode) { owner = j; break; }
        tnode[tid] = (owner == tid) ? mynode : -1;
        if (owner == tid) atomicOr(&bmask[mynode >> 5], 1u << (mynode & 31));
        if (blockIdx.x == 0) {
            tsorted_g[tid] = mynode; towner_g[tid] = owner;
            if (owner == tid) atomicCAS(&fmapRow[mynode], 0, tid * 65 + 0 + 1);  // self row claim
        }
    }
    __syncthreads();
    int n4 = E >> 2;
    for (int idx = blockIdx.x * 256 + tid; idx < n4; idx += gridDim.x * 256) {
        int4 ss = ((const int4*)ei)[idx];
        int4 dd = ((const int4*)(ei + E))[idx];
        int s[4] = {ss.x, ss.y, ss.z, ss.w};
        int d[4] = {dd.x, dd.y, dd.z, dd.w};
        atomicAdd(&cnt[d[0]], 1);   // half the degree atomics (k=0,1)
        atomicAdd(&cnt[d[1]], 1);
#pragma unroll
        for (int k = 0; k < 4; k++) {
            if ((bmask[d[k] >> 5] >> (d[k] & 31)) & 1u) {
                int f = 0;
                for (int j = 0; j < KK; j++) if (tnode[j] == d[k]) { f = j + 1; break; }
                if (f) {
                    int p = atomicAdd(&tcnt2[f - 1], 1);
                    if (p < CAP) {
                        tslots[(f - 1) * CAP + p] = s[k];
                        atomicCAS(&fmapRow[s[k]], 0, (f - 1) * 65 + (p + 1) + 1);  // slot row claim
                    }
                }
            }
        }
    }
    if (blockIdx.x == 0 && tid == 0) {
        for (int e = n4 * 4; e < E; e++) {
            int d = ei[E + e];
            atomicAdd(&cnt[d], 1);
            if ((bmask[d >> 5] >> (d & 31)) & 1u) {
                int f = 0;
                for (int j = 0; j < KK; j++) if (tnode[j] == d) { f = j + 1; break; }
                if (f) {
                    int p = atomicAdd(&tcnt2[f - 1], 1);
                    if (p < CAP) {
                        tslots[(f - 1) * CAP + p] = ei[e];
                        atomicCAS(&fmapRow[ei[e]], 0, (f - 1) * 65 + (p + 1) + 1);
                    }
                }
            }
        }
    }
}

// ---------------- Pass C: frontier collect + other HALF degree atomics ----------------
__global__ __launch_bounds__(256) void k_collect_f(const int* __restrict__ ei, int E,
                                                   const int* __restrict__ fmapRow,
                                                   int* __restrict__ cnt,
                                                   int* __restrict__ fcnt,
                                                   int* __restrict__ fslots) {
    int idx = blockIdx.x * 256 + threadIdx.x;
    int n4 = E >> 2;
    if (idx < n4) {
        int4 ss = ((const int4*)ei)[idx];
        int4 dd = ((const int4*)(ei + E))[idx];
        atomicAdd(&cnt[dd.z], 1);   // other half of degree atomics (k=2,3)
        atomicAdd(&cnt[dd.w], 1);
        int r0 = fmapRow[dd.x], r1 = fmapRow[dd.y], r2 = fmapRow[dd.z], r3 = fmapRow[dd.w];
        if (r0) { int p = atomicAdd(&fcnt[r0 - 1], 1); if (p < CAP) fslots[(size_t)(r0 - 1) * CAP + p] = ss.x; }
        if (r1) { int p = atomicAdd(&fcnt[r1 - 1], 1); if (p < CAP) fslots[(size_t)(r1 - 1) * CAP + p] = ss.y; }
        if (r2) { int p = atomicAdd(&fcnt[r2 - 1], 1); if (p < CAP) fslots[(size_t)(r2 - 1) * CAP + p] = ss.z; }
        if (r3) { int p = atomicAdd(&fcnt[r3 - 1], 1); if (p < CAP) fslots[(size_t)(r3 - 1) * CAP + p] = ss.w; }
    }
    if (idx == 0) {
        for (int e = n4 * 4; e < E; e++) {
            int r = fmapRow[ei[E + e]];   // tail cnt handled in collect_t
            if (r) { int p = atomicAdd(&fcnt[r - 1], 1); if (p < CAP) fslots[(size_t)(r - 1) * CAP + p] = ei[e]; }
        }
    }
}

// ---------------- Tail: layer1 (per-target, redundant) + layer2 + score + last-block softmax ----
// One block per target, 4 waves. Rows shared between targets are recomputed (~3.8x gather
// redundancy, L3-resident) in exchange for: no h1s roundtrip, no score2 latency chain,
// one fewer dispatch, zero cross-block deps except the proven last-block softmax.
__global__ __launch_bounds__(256) void k_tail(const float* __restrict__ x,
                                              const int* __restrict__ tsorted,
                                              const int* __restrict__ towner,
                                              const int* __restrict__ tcnt2,
                                              const int* __restrict__ tslots,
                                              const int* __restrict__ fmapRow,
                                              const int* __restrict__ cnt,
                                              const int* __restrict__ fcnt,
                                              const int* __restrict__ fslots,
                                              const float* __restrict__ W1,
                                              const float* __restrict__ b1,
                                              const float* __restrict__ W2,
                                              const float* __restrict__ b2,
                                              const float* __restrict__ Wr,
                                              float* __restrict__ sc,
                                              int* __restrict__ done,
                                              float* __restrict__ out) {
    __shared__ __align__(16) float W1s[64 * 64];
    __shared__ __align__(16) float W2s[64 * 64];
    __shared__ float zred[4][64];
    int tid = threadIdx.x;
    int lane = tid & 63;
    int wv = tid >> 6;
    for (int j = tid; j < 1024; j += 256) {
        ((float4*)W1s)[j] = ((const float4*)W1)[j];
        ((float4*)W2s)[j] = ((const float4*)W2)[j];
    }
    int tp = blockIdx.x;
    int t = tsorted[tp];
    int own = towner[tp];
    int c = tcnt2[own]; if (c > CAP) c = CAP;      // rows: j=0 (self=t) .. c (tslots)
    const int* sl = tslots + own * CAP;
    float b1v = b1[lane];
    __syncthreads();

    float zt = 0.f;                                 // this wave's partial sum of du*h1[u]
    for (int j = wv; j <= c; j += 4) {
        int u = (j == 0) ? t : sl[j - 1];
        int ri = fmapRow[u] - 1;                    // u's claimed row -> in-neighbor list
        float du = rsqrtf((float)(cnt[u] + 1));
        float acc = du * x[(size_t)u * 64 + lane];
        int cc = fcnt[ri]; if (cc > CAP) cc = CAP;
        const int* fl = fslots + (size_t)ri * CAP;
        int k = 0;
        for (; k + 4 <= cc; k += 4) {
            int u0 = fl[k], u1 = fl[k + 1], u2 = fl[k + 2], u3 = fl[k + 3];
            float f0 = rsqrtf((float)(cnt[u0] + 1));
            float f1 = rsqrtf((float)(cnt[u1] + 1));
            float f2 = rsqrtf((float)(cnt[u2] + 1));
            float f3 = rsqrtf((float)(cnt[u3] + 1));
            acc += f0 * x[(size_t)u0 * 64 + lane] + f1 * x[(size_t)u1 * 64 + lane]
                 + f2 * x[(size_t)u2 * 64 + lane] + f3 * x[(size_t)u3 * 64 + lane];
        }
        for (; k < cc; k++) {
            int uu = fl[k];
            acc += rsqrtf((float)(cnt[uu] + 1)) * x[(size_t)uu * 64 + lane];
        }
        float z = du * acc;
        float h = 0.f;
#pragma unroll
        for (int f = 0; f < 64; f++) h += __shfl(z, f) * W1s[f * 64 + lane];
        h = fmaxf(h + b1v, 0.f);
        zt += du * h;                               // du*h1[u], summed over this wave's rows
    }
    zred[wv][lane] = zt;
    __syncthreads();

    if (wv == 0) {
        float dt = rsqrtf((float)(cnt[t] + 1));
        float z2 = (zred[0][lane] + zred[1][lane] + zred[2][lane] + zred[3][lane]) * dt;
        float acc2 = 0.f;
#pragma unroll
        for (int f = 0; f < 64; f++) acc2 += __shfl(z2, f) * W2s[f * 64 + lane];
        float h2 = fmaxf(acc2 + b2[lane], 0.f);
        float p = h2 * Wr[lane];
#pragma unroll
        for (int off = 32; off >= 1; off >>= 1) p += __shfl_xor(p, off);
        // publish score with agent-scope release; last arriving block runs softmax
        int last = 0;
        if (lane == 0) {
            __hip_atomic_store(&sc[tp], p, __ATOMIC_RELEASE, __HIP_MEMORY_SCOPE_AGENT);
            last = (__hip_atomic_fetch_add(done, 1, __ATOMIC_ACQ_REL, __HIP_MEMORY_SCOPE_AGENT) == KK - 1) ? 1 : 0;
        }
        last = __shfl(last, 0);
        if (last) {
            float s = __hip_atomic_load(&sc[lane], __ATOMIC_ACQUIRE, __HIP_MEMORY_SCOPE_AGENT);
            float m = s;
#pragma unroll
            for (int off = 32; off >= 1; off >>= 1) m = fmaxf(m, __shfl_xor(m, off));
            float e = __expf(s - m);
            float ssum = e;
#pragma unroll
            for (int off = 32; off >= 1; off >>= 1) ssum += __shfl_xor(ssum, off);
            out[lane] = e / ssum;        // br omitted: constant shift cancels in softmax
            out[KK + lane] = (float)tsorted[lane];
        }
    }
}

extern "C" void kernel_launch(void* const* d_in, const int* in_sizes, int n_in,
                              void* d_out, int out_size, void* d_ws, size_t ws_size,
                              hipStream_t stream) {
    const float* x  = (const float*)d_in[0];
    const int*   ei = (const int*)d_in[1];
    const int*   nodep = (const int*)d_in[2];
    const float* W1 = (const float*)d_in[3];
    const float* b1 = (const float*)d_in[4];
    const float* W2 = (const float*)d_in[5];
    const float* b2 = (const float*)d_in[6];
    const float* Wr = (const float*)d_in[7];
    const float* br = (const float*)d_in[8];
    float* out = (float*)d_out;
    (void)br; (void)n_in; (void)out_size; (void)ws_size;

    int N = in_sizes[0] / 64;   // 50000
    int E = in_sizes[1] / 2;    // 800064

    char* w = (char*)d_ws;
    // ---- region zeroed inside k_find (contiguous, int4-aligned) ----
    int* cnt     = (int*)w; w += (size_t)N * 4;    // in-degrees
    int* fmapRow = (int*)w; w += (size_t)N * 4;    // node -> band row+1 (CAS claim)
    int* fcnt    = (int*)w; w += (size_t)NF * 4;
    int* tcnt2   = (int*)w; w += KK * 4;
    int* aux     = (int*)w; w += 16;               // aux[1] = done counter for k_tail
    int zcount4 = (2 * N + NF + KK + 4) / 4;       // 104228 ints -> 26057 int4
    // ---- zeroed by 16B memset (used by k_find itself) ----
    int* tcount = (int*)w; w += 16;
    // ---- non-zeroed ----
    int* tpairs  = (int*)w; w += 2 * KK * 4;
    int* tsorted = (int*)w; w += KK * 4;
    int* towner  = (int*)w; w += KK * 4;
    int* tslots  = (int*)w; w += (size_t)KK * CAP * 4;
    int* fslots  = (int*)w; w += (size_t)NF * CAP * 4;    // ~1.06 MB
    float* sc    = (float*)w; w += KK * 4;

    hipMemsetAsync(tcount, 0, 16, stream);

    int n4 = E >> 2;
    int ebl = (n4 + 255) / 256;
    k_find<<<ebl, 256, 0, stream>>>(ei, E, nodep, (int4*)cnt, zcount4, tcount, tpairs);
    k_collect_t<<<512, 256, 0, stream>>>(ei, E, tpairs, cnt, tcnt2, tslots, fmapRow, tsorted, towner);
    k_collect_f<<<ebl, 256, 0, stream>>>(ei, E, fmapRow, cnt, fcnt, fslots);
    k_tail<<<KK, 256, 0, stream>>>(x, tsorted, towner, tcnt2, tslots, fmapRow,
                                   cnt, fcnt, fslots, W1, b1, W2, b2, Wr, sc, &aux[1], out);
}

// Round 4
// 142.504 us; speedup vs baseline: 1.1943x; 1.1943x over previous
//
#include <hip/hip_runtime.h>
#include <math.h>

#define KK 64
#define CAP 64
#define NF 4160      // 64 targets x (1 self + up to 64 in-edge slots)
#define BMW 1568     // bitmask words for 50k nodes (50176 bits)

__device__ __forceinline__ int fnode_of(int i, const int* tsorted, const int* towner,
                                        const int* tcnt2, const int* tslots) {
    int tp = i / 65, j = i % 65;
    if (j == 0) return tsorted[tp];
    int own = towner[tp];
    int c = tcnt2[own]; if (c > CAP) c = CAP;
    return (j - 1 < c) ? tslots[own * CAP + (j - 1)] : -1;
}

// ---------------- Pass A (read-only): find edges incident to `node`; fused zeroing ----------------
__global__ __launch_bounds__(256) void k_find(const int* __restrict__ ei, int E,
                                              const int* __restrict__ nodep,
                                              int4* __restrict__ zbase, int zcount4,
                                              int* __restrict__ tcount,
                                              int* __restrict__ tpairs) {
    int idx = blockIdx.x * 256 + threadIdx.x;
    if (idx < zcount4) zbase[idx] = make_int4(0, 0, 0, 0);   // cnt/fmapRow/fcnt/tcnt2/aux/needed
    int node = nodep[0];
    int n4 = E >> 2;
    if (idx < n4) {
        int4 ss = ((const int4*)ei)[idx];
        int4 dd = ((const int4*)(ei + E))[idx];
        int s[4] = {ss.x, ss.y, ss.z, ss.w};
        int d[4] = {dd.x, dd.y, dd.z, dd.w};
#pragma unroll
        for (int k = 0; k < 4; k++) {
            if (s[k] == node || d[k] == node) {
                int q = atomicAdd(tcount, 1);
                if (q < KK) { int e = idx * 4 + k; tpairs[2 * q] = e; tpairs[2 * q + 1] = (s[k] == node) ? d[k] : s[k]; }
            }
        }
    }
    if (idx == 0) {
        for (int e = n4 * 4; e < E; e++) {
            int s = ei[e], d = ei[E + e];
            if (s == node || d == node) {
                int q = atomicAdd(tcount, 1);
                if (q < KK) { tpairs[2 * q] = e; tpairs[2 * q + 1] = (s == node) ? d : s; }
            }
        }
    }
}

// ---------------- Pass B: target collect + fmapRow claims + needed-bitmap (NO degree atomics) ----
__global__ __launch_bounds__(256) void k_collect_t(const int* __restrict__ ei, int E,
                                                   const int* __restrict__ tpairs,
                                                   int* __restrict__ tcnt2,
                                                   int* __restrict__ tslots,
                                                   int* __restrict__ fmapRow,
                                                   unsigned int* __restrict__ needed,
                                                   int* __restrict__ tsorted_g,
                                                   int* __restrict__ towner_g) {
    __shared__ unsigned int bmask[BMW];
    __shared__ int tnode[KK];
    __shared__ int eidx[KK], tgt[KK], srt[KK];
    int tid = threadIdx.x;
    for (int i = tid; i < BMW; i += 256) bmask[i] = 0u;
    if (tid < KK) { eidx[tid] = tpairs[2 * tid]; tgt[tid] = tpairs[2 * tid + 1]; }
    __syncthreads();
    if (tid < KK) {
        int rank = 0;
        for (int j = 0; j < KK; j++) rank += (eidx[j] < eidx[tid]) ? 1 : 0;
        srt[rank] = tgt[tid];
    }
    __syncthreads();
    if (tid < KK) {
        int mynode = srt[tid];
        int owner = tid;
        for (int j = 0; j < tid; j++) if (srt[j] == mynode) { owner = j; break; }
        tnode[tid] = (owner == tid) ? mynode : -1;
        if (owner == tid) atomicOr(&bmask[mynode >> 5], 1u << (mynode & 31));
        if (blockIdx.x == 0) {
            tsorted_g[tid] = mynode; towner_g[tid] = owner;
            if (owner == tid) {
                atomicCAS(&fmapRow[mynode], 0, tid * 65 + 0 + 1);    // self row claim
                atomicOr(&needed[mynode >> 5], 1u << (mynode & 31)); // target needs degree
            }
        }
    }
    __syncthreads();
    int n4 = E >> 2;
    for (int idx = blockIdx.x * 256 + tid; idx < n4; idx += gridDim.x * 256) {
        int4 dd = ((const int4*)(ei + E))[idx];
        int d[4] = {dd.x, dd.y, dd.z, dd.w};
#pragma unroll
        for (int k = 0; k < 4; k++) {
            if ((bmask[d[k] >> 5] >> (d[k] & 31)) & 1u) {
                int f = 0;
                for (int j = 0; j < KK; j++) if (tnode[j] == d[k]) { f = j + 1; break; }
                if (f) {
                    int s = ei[idx * 4 + k];               // lazy src load (rare hit path)
                    int p = atomicAdd(&tcnt2[f - 1], 1);
                    if (p < CAP) {
                        tslots[(f - 1) * CAP + p] = s;
                        atomicCAS(&fmapRow[s], 0, (f - 1) * 65 + (p + 1) + 1);  // slot row claim
                        atomicOr(&needed[s >> 5], 1u << (s & 31));              // row node needs degree
                    }
                }
            }
        }
    }
    if (blockIdx.x == 0 && tid == 0) {
        for (int e = n4 * 4; e < E; e++) {
            int d = ei[E + e];
            if ((bmask[d >> 5] >> (d & 31)) & 1u) {
                int f = 0;
                for (int j = 0; j < KK; j++) if (tnode[j] == d) { f = j + 1; break; }
                if (f) {
                    int s = ei[e];
                    int p = atomicAdd(&tcnt2[f - 1], 1);
                    if (p < CAP) {
                        tslots[(f - 1) * CAP + p] = s;
                        atomicCAS(&fmapRow[s], 0, (f - 1) * 65 + (p + 1) + 1);
                        atomicOr(&needed[s >> 5], 1u << (s & 31));
                    }
                }
            }
        }
    }
}

// ---------------- Pass C: frontier collect + needed bits + owner-row compaction (NO degree atomics) ----
__global__ __launch_bounds__(256) void k_collect_f(const int* __restrict__ ei, int E,
                                                   const int* __restrict__ fmapRow,
                                                   int* __restrict__ fcnt,
                                                   int* __restrict__ fslots,
                                                   unsigned int* __restrict__ needed,
                                                   const int* __restrict__ tsorted,
                                                   const int* __restrict__ towner,
                                                   const int* __restrict__ tcnt2,
                                                   const int* __restrict__ tslots,
                                                   int* __restrict__ ownerCount,
                                                   int2* __restrict__ owners) {
    int idx = blockIdx.x * 256 + threadIdx.x;
    // owner-row compaction: rows are final after k_collect_t; build dense (row, node) list
    if (idx < NF) {
        int u = fnode_of(idx, tsorted, towner, tcnt2, tslots);
        if (u >= 0 && fmapRow[u] == idx + 1) {
            int p = atomicAdd(ownerCount, 1);
            owners[p] = make_int2(idx, u);
        }
    }
    int n4 = E >> 2;
    if (idx < n4) {
        int4 dd = ((const int4*)(ei + E))[idx];
        int r0 = fmapRow[dd.x], r1 = fmapRow[dd.y], r2 = fmapRow[dd.z], r3 = fmapRow[dd.w];
        if (r0) { int s = ei[idx * 4 + 0]; int p = atomicAdd(&fcnt[r0 - 1], 1);
                  if (p < CAP) { fslots[(size_t)(r0 - 1) * CAP + p] = s; atomicOr(&needed[s >> 5], 1u << (s & 31)); } }
        if (r1) { int s = ei[idx * 4 + 1]; int p = atomicAdd(&fcnt[r1 - 1], 1);
                  if (p < CAP) { fslots[(size_t)(r1 - 1) * CAP + p] = s; atomicOr(&needed[s >> 5], 1u << (s & 31)); } }
        if (r2) { int s = ei[idx * 4 + 2]; int p = atomicAdd(&fcnt[r2 - 1], 1);
                  if (p < CAP) { fslots[(size_t)(r2 - 1) * CAP + p] = s; atomicOr(&needed[s >> 5], 1u << (s & 31)); } }
        if (r3) { int s = ei[idx * 4 + 3]; int p = atomicAdd(&fcnt[r3 - 1], 1);
                  if (p < CAP) { fslots[(size_t)(r3 - 1) * CAP + p] = s; atomicOr(&needed[s >> 5], 1u << (s & 31)); } }
    }
    if (idx == 0) {
        for (int e = n4 * 4; e < E; e++) {
            int r = fmapRow[ei[E + e]];
            if (r) { int s = ei[e]; int p = atomicAdd(&fcnt[r - 1], 1);
                     if (p < CAP) { fslots[(size_t)(r - 1) * CAP + p] = s; atomicOr(&needed[s >> 5], 1u << (s & 31)); } }
        }
    }
}

// ---------------- Pass D: filtered degree count — atomics only for needed nodes (~270K of 800K) ----
__global__ __launch_bounds__(256) void k_deg(const int* __restrict__ ei, int E,
                                             const unsigned int* __restrict__ needed,
                                             int* __restrict__ cnt) {
    int idx = blockIdx.x * 256 + threadIdx.x;
    int n4 = E >> 2;
    if (idx < n4) {
        int4 dd = ((const int4*)(ei + E))[idx];   // dst stream only (3.2 MB)
        int d[4] = {dd.x, dd.y, dd.z, dd.w};
#pragma unroll
        for (int k = 0; k < 4; k++)
            if ((needed[d[k] >> 5] >> (d[k] & 31)) & 1u)   // 6.25 KB bitmap: L1-resident
                atomicAdd(&cnt[d[k]], 1);
    }
    if (idx == 0) {
        for (int e = n4 * 4; e < E; e++) {
            int d = ei[E + e];
            if ((needed[d >> 5] >> (d & 31)) & 1u) atomicAdd(&cnt[d], 1);
        }
    }
}

// ---------------- Layer 1 (dense owner list): gather+norm, W1 shfl-GEMM ----------------
__global__ __launch_bounds__(256) void k_layer1(const float* __restrict__ x,
                                                const int2* __restrict__ owners,
                                                const int* __restrict__ ownerCount,
                                                const int* __restrict__ cnt,
                                                const int* __restrict__ fcnt,
                                                const int* __restrict__ fslots,
                                                const float* __restrict__ W1,
                                                const float* __restrict__ b1,
                                                float* __restrict__ h1s) {
    __shared__ __align__(16) float W1s[64 * 64];
    int tid = threadIdx.x;
    int nown = ownerCount[0];
    int ngrp = (nown + 3) >> 2;
    if ((int)blockIdx.x >= ngrp) return;          // tail blocks: exit before W1 load
    for (int j = tid; j < 1024; j += 256) ((float4*)W1s)[j] = ((const float4*)W1)[j];
    __syncthreads();
    int lane = tid & 63;
    for (int g = blockIdx.x; g < ngrp; g += gridDim.x) {
        int idx = g * 4 + (tid >> 6);
        if (idx >= nown) continue;                // wave-uniform
        int2 ou = owners[idx];
        int i = ou.x, u = ou.y;
        float du = rsqrtf((float)(cnt[u] + 1));
        float acc = du * x[(size_t)u * 64 + lane];
        int c = fcnt[i]; if (c > CAP) c = CAP;
        const int* sl = fslots + (size_t)i * CAP;
        int k = 0;
        for (; k + 4 <= c; k += 4) {
            int u0 = sl[k], u1 = sl[k + 1], u2 = sl[k + 2], u3 = sl[k + 3];
            float f0 = rsqrtf((float)(cnt[u0] + 1));
            float f1 = rsqrtf((float)(cnt[u1] + 1));
            float f2 = rsqrtf((float)(cnt[u2] + 1));
            float f3 = rsqrtf((float)(cnt[u3] + 1));
            acc += f0 * x[(size_t)u0 * 64 + lane] + f1 * x[(size_t)u1 * 64 + lane]
                 + f2 * x[(size_t)u2 * 64 + lane] + f3 * x[(size_t)u3 * 64 + lane];
        }
        for (; k < c; k++) {
            int uu = sl[k];
            acc += rsqrtf((float)(cnt[uu] + 1)) * x[(size_t)uu * 64 + lane];
        }
        float z = du * acc;
        float h = 0.f;
#pragma unroll
        for (int f = 0; f < 64; f++) h += __shfl(z, f) * W1s[f * 64 + lane];
        h = fmaxf(h + b1[lane], 0.f);
        h1s[(size_t)i * 64 + lane] = du * h;
    }
}

// ---------------- Layer 2 + raw score + fused softmax (last block) ----------------
__global__ __launch_bounds__(64) void k_score2(const float* __restrict__ h1s,
                                               const int* __restrict__ tsorted,
                                               const int* __restrict__ towner,
                                               const int* __restrict__ tcnt2,
                                               const int* __restrict__ tslots,
                                               const int* __restrict__ fmapRow,
                                               const int* __restrict__ cnt,
                                               const float* __restrict__ W2,
                                               const float* __restrict__ b2,
                                               const float* __restrict__ Wr,
                                               float* __restrict__ sc,
                                               int* __restrict__ done,
                                               float* __restrict__ out) {
    int tp = blockIdx.x;
    int lane = threadIdx.x;
    int t = tsorted[tp];
    float dt = rsqrtf((float)(cnt[t] + 1));
    int own = towner[tp];
    int c = tcnt2[own]; if (c > CAP) c = CAP;
    const int* sl = tslots + own * CAP;
    // j=0: self row via fmapRow[t]
    float z = h1s[(size_t)(fmapRow[t] - 1) * 64 + lane];
#pragma unroll 8
    for (int j = 0; j < c; j++) {
        int u = sl[j];                        // wave-uniform scalar loads, independent
        int row = fmapRow[u] - 1;             // depth-2 chain, pipelined across j
        z += h1s[(size_t)row * 64 + lane];
    }
    z *= dt;
    float acc = 0.f;
#pragma unroll
    for (int f = 0; f < 64; f++) acc += __shfl(z, f) * W2[f * 64 + lane];
    float h2 = fmaxf(acc + b2[lane], 0.f);
    float p = h2 * Wr[lane];
#pragma unroll
    for (int off = 32; off >= 1; off >>= 1) p += __shfl_xor(p, off);
    // publish score with agent-scope release; last arriving block runs softmax
    int last = 0;
    if (lane == 0) {
        __hip_atomic_store(&sc[tp], p, __ATOMIC_RELEASE, __HIP_MEMORY_SCOPE_AGENT);
        last = (__hip_atomic_fetch_add(done, 1, __ATOMIC_ACQ_REL, __HIP_MEMORY_SCOPE_AGENT) == KK - 1) ? 1 : 0;
    }
    last = __shfl(last, 0);
    if (last) {
        float s = __hip_atomic_load(&sc[lane], __ATOMIC_ACQUIRE, __HIP_MEMORY_SCOPE_AGENT);
        float m = s;
#pragma unroll
        for (int off = 32; off >= 1; off >>= 1) m = fmaxf(m, __shfl_xor(m, off));
        float e = __expf(s - m);
        float ssum = e;
#pragma unroll
        for (int off = 32; off >= 1; off >>= 1) ssum += __shfl_xor(ssum, off);
        out[lane] = e / ssum;        // br omitted: constant shift cancels in softmax
        out[KK + lane] = (float)tsorted[lane];
    }
}

extern "C" void kernel_launch(void* const* d_in, const int* in_sizes, int n_in,
                              void* d_out, int out_size, void* d_ws, size_t ws_size,
                              hipStream_t stream) {
    const float* x  = (const float*)d_in[0];
    const int*   ei = (const int*)d_in[1];
    const int*   nodep = (const int*)d_in[2];
    const float* W1 = (const float*)d_in[3];
    const float* b1 = (const float*)d_in[4];
    const float* W2 = (const float*)d_in[5];
    const float* b2 = (const float*)d_in[6];
    const float* Wr = (const float*)d_in[7];
    const float* br = (const float*)d_in[8];
    float* out = (float*)d_out;
    (void)br; (void)n_in; (void)out_size; (void)ws_size;

    int N = in_sizes[0] / 64;   // 50000
    int E = in_sizes[1] / 2;    // 800064

    char* w = (char*)d_ws;
    // ---- region zeroed inside k_find (contiguous, int4-aligned) ----
    int* cnt     = (int*)w; w += (size_t)N * 4;    // in-degrees (needed nodes only)
    int* fmapRow = (int*)w; w += (size_t)N * 4;    // node -> band row+1 (CAS claim)
    int* fcnt    = (int*)w; w += (size_t)NF * 4;
    int* tcnt2   = (int*)w; w += KK * 4;
    int* aux     = (int*)w; w += 16;               // aux[0]=ownerCount, aux[1]=done
    unsigned int* needed = (unsigned int*)w; w += BMW * 4;   // node-needs-degree bitmap
    int zcount4 = (2 * N + NF + KK + 4 + BMW) / 4; // 105796 ints -> 26449 int4
    // ---- zeroed by 16B memset (used by k_find itself) ----
    int* tcount = (int*)w; w += 16;
    // ---- non-zeroed ----
    int* tpairs  = (int*)w; w += 2 * KK * 4;
    int* tsorted = (int*)w; w += KK * 4;
    int* towner  = (int*)w; w += KK * 4;
    int* tslots  = (int*)w; w += (size_t)KK * CAP * 4;
    int2* owners = (int2*)w; w += (size_t)NF * 8;         // dense (row, node) list
    int* fslots  = (int*)w; w += (size_t)NF * CAP * 4;    // ~1.06 MB
    float* h1s   = (float*)w; w += (size_t)NF * 64 * 4;   // ~1.06 MB
    float* sc    = (float*)w; w += KK * 4;

    hipMemsetAsync(tcount, 0, 16, stream);

    int n4 = E >> 2;
    int ebl = (n4 + 255) / 256;
    k_find<<<ebl, 256, 0, stream>>>(ei, E, nodep, (int4*)cnt, zcount4, tcount, tpairs);
    k_collect_t<<<512, 256, 0, stream>>>(ei, E, tpairs, tcnt2, tslots, fmapRow, needed, tsorted, towner);
    k_collect_f<<<ebl, 256, 0, stream>>>(ei, E, fmapRow, fcnt, fslots, needed,
                                         tsorted, towner, tcnt2, tslots, &aux[0], owners);
    k_deg<<<ebl, 256, 0, stream>>>(ei, E, needed, cnt);
    k_layer1<<<288, 256, 0, stream>>>(x, owners, &aux[0], cnt, fcnt, fslots, W1, b1, h1s);
    k_score2<<<KK, 64, 0, stream>>>(h1s, tsorted, towner, tcnt2, tslots, fmapRow,
                                    cnt, W2, b2, Wr, sc, &aux[1], out);
}